// Round 8
// baseline (265.628 us; speedup 1.0000x reference)
//
#include <hip/hip_runtime.h>
#include <hip/hip_bf16.h>

// Discriminator pipeline. R8: 8 dispatches.
//   layout(+wprep +zero stats) -> conv1(+BN1 stats) -> bnapply1 (BN1 inline)
//   -> conv2(+BN2 stats, 2 batches/wave) -> bnapply2t (BN2 inline)
//   -> fc1 (LDS-free direct-global A, 144-way split-K) -> fc1_reduce(+BN3)
//   -> fc2 (BN3 inline + sigmoid).
// conv/fc biases absorbed by the following BN. BN scale/shift computed
// redundantly per consumer block from fp32 atomic sums.
//
// MFMA convention (verified m89/m91): D = mfma(a,b,c): D[m][n] = sum_k
// A[m][k]*B[n][k]; a: lane(f=m&15,q=lane>>4) elem j = A[f][q*8+j]; b same
// with f=n; d: lane l reg r = D[(l>>4)*4+r][l&15].

typedef unsigned short u16;
typedef __attribute__((ext_vector_type(8))) short bf8_t;
typedef __attribute__((ext_vector_type(4))) float f4_t;
#define MFMA16(a, b, c) __builtin_amdgcn_mfma_f32_16x16x32_bf16(a, b, c, 0, 0, 0)

#define LEAKY(v) (fmaxf((v), 0.2f * (v)))
#define CLIP01(v) fminf(fmaxf((v), 0.0f), 1.0f)

__device__ inline unsigned f2bf(float f) {  // RNE fp32->bf16 (low 16 bits)
  unsigned u = __float_as_uint(f);
  return (u + 0x7FFFu + ((u >> 16) & 1u)) >> 16;
}
__device__ inline float bf2f(unsigned u) { return __uint_as_float(u << 16); }

constexpr int HW = 108;
constexpr int NOBJ = 16;
constexpr int NCLS = 7;

// ---------------- layout_bbox -> NHWC8 bf16 (+ weight prep in first 114 blocks)
__global__ __launch_bounds__(128) void layout_prep_kernel(
    const float* __restrict__ image, const float* __restrict__ w1,
    const float* __restrict__ w2, u16* __restrict__ lay8,
    u16* __restrict__ wB1, u16* __restrict__ wB2, float* __restrict__ st) {
  int h = blockIdx.x, b = blockIdx.y;
  int tid = threadIdx.x;
  int bid = b * 108 + h;
  if (bid < 114) {  // 114 * 512 = 58368 prep items
#pragma unroll
    for (int j = 0; j < 4; ++j) {
      int i = bid * 512 + j * 128 + tid;
      if (i < 1216) st[i] = 0.f;
      if (i < 7168) {
        int co = i / 224, k = i % 224;
        int chunk = k >> 5, kk = k & 31, tl = kk >> 3, ci = kk & 7;
        int tap = chunk * 4 + tl;
        unsigned v = 0;
        if (tap < 25 && ci < 7) v = f2bf(w1[co * 175 + ci * 25 + tap]);
        wB1[i] = (u16)v;
      } else if (i < 58368) {
        int jj = i - 7168;  // < 51200
        int tap = jj / 2048, r = jj % 2048, co = r >> 5, ci = r & 31;
        wB2[jj] = (u16)f2bf(w2[co * 800 + ci * 25 + tap]);
      }
    }
  }
  __shared__ float sIm[NOBJ * 11];
  for (int i = tid; i < NOBJ * 11; i += 128) sIm[i] = image[b * NOBJ * 11 + i];
  __syncthreads();
  int w = tid;
  if (w >= HW) return;
  float best[NCLS];
#pragma unroll
  for (int c = 0; c < NCLS; ++c) best[c] = 0.0f;
  float fw = (float)w, fh = (float)h;
  for (int o = 0; o < NOBJ; ++o) {
    const float* p = &sIm[o * 11];
    float xc = p[0] * 108.0f, yc = p[1] * 108.0f;
    float wd = p[2] * 108.0f, hd = p[3] * 108.0f;
    float x1 = xc - 0.5f * wd, x2 = xc + 0.5f * wd;
    float y1 = yc - 0.5f * hd, y2 = yc + 0.5f * hd;
    float x1d = fw - x1, x2d = x2 - fw;
    float y1d = fh - y1, y2d = y2 - fh;
    float yband = CLIP01(y1d) * CLIP01(y2d);
    float xband = CLIP01(x1d) * CLIP01(x2d);
    float x1l = fmaxf(1.0f - fabsf(x1d), 0.0f) * yband;
    float x2l = fmaxf(1.0f - fabsf(x2d), 0.0f) * yband;
    float y1l = fmaxf(1.0f - fabsf(y1d), 0.0f) * xband;
    float y2l = fmaxf(1.0f - fabsf(y2d), 0.0f) * xband;
    float xy = fmaxf(fmaxf(x1l, x2l), fmaxf(y1l, y2l));
#pragma unroll
    for (int c = 0; c < NCLS; ++c) best[c] = fmaxf(best[c], xy * p[4 + c]);
  }
  unsigned p0 = f2bf(best[0]) | (f2bf(best[1]) << 16);
  unsigned p1 = f2bf(best[2]) | (f2bf(best[3]) << 16);
  unsigned p2 = f2bf(best[4]) | (f2bf(best[5]) << 16);
  unsigned p3 = f2bf(best[6]);
  uint4 stv = {p0, p1, p2, p3};
  ((uint4*)lay8)[b * 11664 + h * 108 + w] = stv;
}

// --------------------------------------------------------------- conv1 MFMA
// grid (43 mt4, 2 nt, 16 bz), block 128 = 2 waves.
// wave: 4 m-tiles, 1 n-tile, 2 batches. BN1 stats: lane xor-reduce +
// cross-wave LDS reduce -> 1 atomic/block/co (688/address).
__global__ __launch_bounds__(128) void conv1_mfma(
    const u16* __restrict__ lay8, const u16* __restrict__ wB1,
    u16* __restrict__ x1r, float* __restrict__ bn1sum,
    float* __restrict__ bn1sq) {
  int mtg = blockIdx.x, nt = blockIdx.y, bz = blockIdx.z;
  int tid = threadIdx.x;
  int lane = tid & 63, wv = tid >> 6;
  int f = lane & 15, q = lane >> 4;
  int co = nt * 16 + f;
  int b0 = bz * 4 + wv * 2;
  int pbase[4];
  bool mvalid[4];
#pragma unroll
  for (int t = 0; t < 4; ++t) {
    int mt = mtg * 4 + t;
    mvalid[t] = mt < 169;
    int P = min(mt * 16 + f, 2703);
    int oh = P / 52, ow = P - oh * 52;
    pbase[t] = (oh * 2 * 108 + ow * 2) * 8;
  }
  f4_t acc[2][4];
#pragma unroll
  for (int b2 = 0; b2 < 2; ++b2)
#pragma unroll
    for (int t = 0; t < 4; ++t) acc[b2][t] = {0.f, 0.f, 0.f, 0.f};
#pragma unroll
  for (int chunk = 0; chunk < 7; ++chunk) {
    int tap = chunk * 4 + q;
    tap = tap > 24 ? 24 : tap;  // dup taps carry zero weights
    int kh = tap / 5, kw = tap - kh * 5;
    int toff = (kh * 108 + kw) * 8;
    bf8_t bf = *(const bf8_t*)&wB1[co * 224 + chunk * 32 + q * 8];
#pragma unroll
    for (int b2 = 0; b2 < 2; ++b2) {
      const u16* lb = lay8 + (size_t)(b0 + b2) * 93312;
#pragma unroll
      for (int t = 0; t < 4; ++t) {
        bf8_t af = *(const bf8_t*)&lb[pbase[t] + toff];
        acc[b2][t] = MFMA16(af, bf, acc[b2][t]);
      }
    }
  }
  float s = 0.f, sq = 0.f;
#pragma unroll
  for (int b2 = 0; b2 < 2; ++b2) {
    u16* ob = x1r + (size_t)(b0 + b2) * 86528;
#pragma unroll
    for (int t = 0; t < 4; ++t) {
      if (!mvalid[t]) continue;
      int P0 = (mtg * 4 + t) * 16 + q * 4;
#pragma unroll
      for (int r = 0; r < 4; ++r) {
        float v = acc[b2][t][r];
        s += v;
        sq += v * v;
        ob[(P0 + r) * 32 + co] = (u16)f2bf(v);
      }
    }
  }
  s += __shfl_xor(s, 16);
  s += __shfl_xor(s, 32);
  sq += __shfl_xor(sq, 16);
  sq += __shfl_xor(sq, 32);
  __shared__ float rs[2][16], rq[2][16];
  if (lane < 16) {
    rs[wv][f] = s;
    rq[wv][f] = sq;
  }
  __syncthreads();
  if (tid < 16) {
    atomicAdd(&bn1sum[nt * 16 + tid], rs[0][tid] + rs[1][tid]);
    atomicAdd(&bn1sq[nt * 16 + tid], rq[0][tid] + rq[1][tid]);
  }
}

// ------------- BN1 finalize(inline)+leaky: x1r bf16 -> x1b bf16, 8/thread
__global__ __launch_bounds__(256) void bnapply1_kernel(
    const u16* __restrict__ x1r, const float* __restrict__ bn1sum,
    const float* __restrict__ bn1sq, const float* __restrict__ g1,
    const float* __restrict__ b1, u16* __restrict__ x1b) {
  int idx = blockIdx.x * 256 + threadIdx.x;  // 692,224
  int base = idx * 8, c0 = base & 31;
  float sc[8], sh[8];
#pragma unroll
  for (int j = 0; j < 8; ++j) {
    int c = c0 + j;
    float mean = bn1sum[c] * (1.f / 173056.f);
    float var = bn1sq[c] * (1.f / 173056.f) - mean * mean;
    float s = g1[c] * rsqrtf(var + 1e-5f);
    sc[j] = s;
    sh[j] = b1[c] - mean * s;
  }
  uint4 in = *(const uint4*)&x1r[base];
  unsigned w[4] = {in.x, in.y, in.z, in.w};
  unsigned out[4];
#pragma unroll
  for (int j = 0; j < 4; ++j) {
    float a = bf2f(w[j] & 0xffffu);
    float bq = bf2f(w[j] >> 16);
    a = LEAKY(fmaf(a, sc[2 * j], sh[2 * j]));
    bq = LEAKY(fmaf(bq, sc[2 * j + 1], sh[2 * j + 1]));
    out[j] = f2bf(a) | (f2bf(bq) << 16);
  }
  uint4 stv = {out[0], out[1], out[2], out[3]};
  *(uint4*)&x1b[base] = stv;
}

// --------------------------------------------------------------- conv2 MFMA
// grid (36 mt, 4 nt, 8 bz), block 256 = 4 waves.
// wave: 1 m-tile, 1 n-tile, 2 batches (bz*8 + wv*2 + b2). LDS-free compute;
// BN2 stats via cross-wave LDS reduce -> 288 atomics/address.
__global__ __launch_bounds__(256) void conv2_mfma(
    const u16* __restrict__ x1b, const u16* __restrict__ wB2,
    float* __restrict__ x2c, float* __restrict__ bn2sum,
    float* __restrict__ bn2sq) {
  int mt = blockIdx.x, nt = blockIdx.y, bz = blockIdx.z;
  int tid = threadIdx.x;
  int lane = tid & 63, wv = tid >> 6;
  int f = lane & 15, q = lane >> 4;
  int co = nt * 16 + f;
  int b0 = bz * 8 + wv * 2;
  int P = mt * 16 + f;
  int oh = P / 24, ow = P - oh * 24;
  int abase = (oh * 2 * 52 + ow * 2) * 32 + q * 8;
  f4_t acc[2];
#pragma unroll
  for (int b2 = 0; b2 < 2; ++b2) acc[b2] = {0.f, 0.f, 0.f, 0.f};
#pragma unroll
  for (int tap = 0; tap < 25; ++tap) {
    int kh = tap / 5, kw = tap - kh * 5;
    int toff = (kh * 52 + kw) * 32;
    bf8_t bf = *(const bf8_t*)&wB2[tap * 2048 + co * 32 + q * 8];
#pragma unroll
    for (int b2 = 0; b2 < 2; ++b2) {
      bf8_t af =
          *(const bf8_t*)&x1b[(size_t)(b0 + b2) * 86528 + abase + toff];
      acc[b2] = MFMA16(af, bf, acc[b2]);
    }
  }
  float s = 0.f, sq = 0.f;
#pragma unroll
  for (int b2 = 0; b2 < 2; ++b2) {
    float* ob = x2c + (size_t)(b0 + b2) * 36864;
#pragma unroll
    for (int r = 0; r < 4; ++r) {
      float v = acc[b2][r];
      s += v;
      sq += v * v;
      ob[(mt * 16 + q * 4 + r) * 64 + co] = v;
    }
  }
  s += __shfl_xor(s, 16);
  s += __shfl_xor(s, 32);
  sq += __shfl_xor(sq, 16);
  sq += __shfl_xor(sq, 32);
  __shared__ float rs[4][16], rq[4][16];
  if (lane < 16) {
    rs[wv][f] = s;
    rq[wv][f] = sq;
  }
  __syncthreads();
  if (tid < 16) {
    atomicAdd(&bn2sum[nt * 16 + tid],
              rs[0][tid] + rs[1][tid] + rs[2][tid] + rs[3][tid]);
    atomicAdd(&bn2sq[nt * 16 + tid],
              rq[0][tid] + rq[1][tid] + rq[2][tid] + rq[3][tid]);
  }
}

// ---- BN2 finalize(inline)+leaky + NHWC->NCHW: x2c -> xB bf16 [b][64*576]
__global__ __launch_bounds__(256) void bnapply2t_kernel(
    const float* __restrict__ x2c, const float* __restrict__ bn2sum,
    const float* __restrict__ bn2sq, const float* __restrict__ g2,
    const float* __restrict__ b2, u16* __restrict__ xB) {
  int hw0 = blockIdx.x * 64, b = blockIdx.y;
  __shared__ float tile[64 * 65];
  int t = threadIdx.x;
  int c = t & 63, hl4 = t >> 6;
  float mean = bn2sum[c] * (1.f / 36864.f);
  float var = bn2sq[c] * (1.f / 36864.f) - mean * mean;
  float s = g2[c] * rsqrtf(var + 1e-5f);
  float h = b2[c] - mean * s;
#pragma unroll
  for (int it = 0; it < 16; ++it) {
    int hl = it * 4 + hl4;
    float v = x2c[((size_t)b * 576 + hw0 + hl) * 64 + c];
    tile[hl * 65 + c] = LEAKY(fmaf(v, s, h));
  }
  __syncthreads();
  int hw = t & 63, cl4 = t >> 6;
#pragma unroll
  for (int it = 0; it < 16; ++it) {
    int cc = it * 4 + cl4;
    xB[(size_t)b * 36864 + cc * 576 + hw0 + hw] = (u16)f2bf(tile[hw * 65 + cc]);
  }
}

// ----------------------------------------------------------------- fc1 MFMA
// part[ks][64][512]: A bf16 [64][36864] (L2-resident, read direct from
// global — no LDS, no barriers, no bank conflicts) x W fp32[512][36864]
// (cvt in-flight). grid (144 ks, 8 nb), block 256 = 4 waves (4 n-tiles);
// k-range 256/block.
__global__ __launch_bounds__(256) void fc1_mfma(
    const u16* __restrict__ xB, const float* __restrict__ wgt,
    float* __restrict__ part) {
  int ks = blockIdx.x, nb = blockIdx.y;
  int tid = threadIdx.x;
  int lane = tid & 63, wv = tid >> 6;
  int f = lane & 15, q = lane >> 4;
  int n0 = nb * 64 + wv * 16;
  int kbase = ks * 256;
  f4_t acc[4];
#pragma unroll
  for (int m = 0; m < 4; ++m) acc[m] = {0.f, 0.f, 0.f, 0.f};
  const float* wrow = wgt + (size_t)(n0 + f) * 36864 + kbase + q * 8;
  const u16* arow = xB + kbase + q * 8;
#pragma unroll
  for (int kt = 0; kt < 8; ++kt) {
    const float* wp = wrow + kt * 32;
    float4 wa = *(const float4*)wp;
    float4 wb = *(const float4*)(wp + 4);
    union { bf8_t v; u16 u[8]; } bu;
    bu.u[0] = (u16)f2bf(wa.x); bu.u[1] = (u16)f2bf(wa.y);
    bu.u[2] = (u16)f2bf(wa.z); bu.u[3] = (u16)f2bf(wa.w);
    bu.u[4] = (u16)f2bf(wb.x); bu.u[5] = (u16)f2bf(wb.y);
    bu.u[6] = (u16)f2bf(wb.z); bu.u[7] = (u16)f2bf(wb.w);
    bf8_t afr[4];
#pragma unroll
    for (int m = 0; m < 4; ++m)
      afr[m] = *(const bf8_t*)&arow[(size_t)(m * 16 + f) * 36864 + kt * 32];
#pragma unroll
    for (int m = 0; m < 4; ++m) acc[m] = MFMA16(afr[m], bu.v, acc[m]);
  }
  float* pp = part + (size_t)ks * 32768;
#pragma unroll
  for (int m = 0; m < 4; ++m)
#pragma unroll
    for (int r = 0; r < 4; ++r)
      pp[(m * 16 + q * 4 + r) * 512 + n0 + f] = acc[m][r];
}

// --------------- fc1_reduce: sum 144 partials -> fc1o; fused BN3 stat atomics
__global__ __launch_bounds__(256) void fc1_reduce_kernel(
    const float* __restrict__ part, float* __restrict__ fc1o,
    float* __restrict__ bn3sum, float* __restrict__ bn3sq) {
  int i = blockIdx.x * 256 + threadIdx.x;  // 0..32767
  float s = 0.f;
#pragma unroll 8
  for (int ks = 0; ks < 144; ++ks) s += part[(size_t)ks * 32768 + i];
  fc1o[i] = s;
  atomicAdd(&bn3sum[i & 511], s);
  atomicAdd(&bn3sq[i & 511], s * s);
}

// ------------------------- fc2: BN3 inline + leaky + dot + sigmoid
__global__ __launch_bounds__(64) void fc2_kernel(
    const float* __restrict__ fc1o, const float* __restrict__ bn3sum,
    const float* __restrict__ bn3sq, const float* __restrict__ g3,
    const float* __restrict__ b3, const float* __restrict__ w2,
    const float* __restrict__ b2o, float* __restrict__ out) {
  int m = blockIdx.x;
  int fl = threadIdx.x;
  float a = 0.f;
#pragma unroll
  for (int j = 0; j < 8; ++j) {
    int ff = fl + j * 64;
    float mean = bn3sum[ff] * (1.f / 64.f);
    float var = bn3sq[ff] * (1.f / 64.f) - mean * mean;
    float sc = g3[ff] * rsqrtf(var + 1e-5f);
    float sh = b3[ff] - mean * sc;
    float v = LEAKY(fmaf(fc1o[m * 512 + ff], sc, sh));
    a += v * w2[ff];
  }
  for (int off = 32; off; off >>= 1) a += __shfl_down(a, off, 64);
  if (fl == 0) out[m] = 1.f / (1.f + expf(-(a + b2o[0])));
}

extern "C" void kernel_launch(void* const* d_in, const int* in_sizes, int n_in,
                              void* d_out, int out_size, void* d_ws,
                              size_t ws_size, hipStream_t stream) {
  const float* image = (const float*)d_in[0];
  const float* c1w = (const float*)d_in[1];
  const float* bn1g = (const float*)d_in[3];
  const float* bn1b = (const float*)d_in[4];
  const float* c2w = (const float*)d_in[5];
  const float* bn2g = (const float*)d_in[7];
  const float* bn2b = (const float*)d_in[8];
  const float* f1w = (const float*)d_in[9];
  const float* bn3g = (const float*)d_in[11];
  const float* bn3b = (const float*)d_in[12];
  const float* f2w = (const float*)d_in[13];
  const float* f2b = (const float*)d_in[14];
  float* ws = (float*)d_ws;

  // Workspace (float units), linear (~67.4 MB of 302 MB; no aliasing):
  u16* lay8 = (u16*)ws;                    // @0          (2,985,984 f)
  u16* x1r = (u16*)(ws + 2985984);         // 2,768,896 f
  u16* x1b = (u16*)(ws + 5754880);         // 2,768,896 f
  float* x2c = ws + 8523776;               // 2,359,296 f
  u16* xB = (u16*)(ws + 10883072);         // 1,179,648 f
  float* fc1part = ws + 12062720;          // 4,718,592 f (144*32768)
  float* fc1o = ws + 16781312;             // 32,768 f
  float* st = ws + 16814080;               // 1,216 f (zeroed by layout_prep)
  float* bn1sum = st, *bn1sq = st + 32;
  float* bn2sum = st + 64, *bn2sq = st + 128;
  float* bn3sum = st + 192, *bn3sq = st + 704;
  u16* wB1 = (u16*)(ws + 16815296);        // 7,168 u16
  u16* wB2 = (u16*)(ws + 16818880);        // 51,200 u16

  layout_prep_kernel<<<dim3(108, 64), 128, 0, stream>>>(image, c1w, c2w, lay8,
                                                        wB1, wB2, st);
  conv1_mfma<<<dim3(43, 2, 16), 128, 0, stream>>>(lay8, wB1, x1r, bn1sum,
                                                  bn1sq);
  bnapply1_kernel<<<2704, 256, 0, stream>>>(x1r, bn1sum, bn1sq, bn1g, bn1b,
                                            x1b);
  conv2_mfma<<<dim3(36, 4, 8), 256, 0, stream>>>(x1b, wB2, x2c, bn2sum,
                                                 bn2sq);
  bnapply2t_kernel<<<dim3(9, 64), 256, 0, stream>>>(x2c, bn2sum, bn2sq, bn2g,
                                                    bn2b, xB);
  fc1_mfma<<<dim3(144, 8), 256, 0, stream>>>(xB, f1w, fc1part);
  fc1_reduce_kernel<<<128, 256, 0, stream>>>(fc1part, fc1o, bn3sum, bn3sq);
  fc2_kernel<<<64, 64, 0, stream>>>(fc1o, bn3sum, bn3sq, bn3g, bn3b, f2w, f2b,
                                    (float*)d_out);
}

// Round 9
// 249.656 us; speedup vs baseline: 1.0640x; 1.0640x over previous
//
#include <hip/hip_runtime.h>
#include <hip/hip_bf16.h>

// Discriminator pipeline. R9 = R7 structure (measured best) + merged wprep +
// conv2 bf16 output. 8 dispatches:
//   layout(+wprep +zero stats) -> conv1(+BN1 stats) -> bnapply1 (BN1 inline)
//   -> conv2(4 batches/wave, +BN2 stats, bf16 out) -> bnapply2t (BN2 inline)
//   -> fc1 (LDS-staged A, 72-way split-K) -> fc1_reduce(+BN3 stats)
//   -> fc2 (BN3 inline + sigmoid).
// conv/fc biases absorbed by the following BN. BN scale/shift computed
// redundantly per consumer block from fp32 atomic sums.
//
// MFMA convention (verified m89/m91): D = mfma(a,b,c): D[m][n] = sum_k
// A[m][k]*B[n][k]; a: lane(f=m&15,q=lane>>4) elem j = A[f][q*8+j]; b same
// with f=n; d: lane l reg r = D[(l>>4)*4+r][l&15].
// fc1 LDS tile pad: row stride 520 u16 = 260 words = 4 mod 32 -> 2-way bank
// alias only (free per m136). Do NOT remove the pad (32-row stride = 8-way).

typedef unsigned short u16;
typedef __attribute__((ext_vector_type(8))) short bf8_t;
typedef __attribute__((ext_vector_type(4))) float f4_t;
#define MFMA16(a, b, c) __builtin_amdgcn_mfma_f32_16x16x32_bf16(a, b, c, 0, 0, 0)

#define LEAKY(v) (fmaxf((v), 0.2f * (v)))
#define CLIP01(v) fminf(fmaxf((v), 0.0f), 1.0f)

__device__ inline unsigned f2bf(float f) {  // RNE fp32->bf16 (low 16 bits)
  unsigned u = __float_as_uint(f);
  return (u + 0x7FFFu + ((u >> 16) & 1u)) >> 16;
}
__device__ inline float bf2f(unsigned u) { return __uint_as_float(u << 16); }

constexpr int HW = 108;
constexpr int NOBJ = 16;
constexpr int NCLS = 7;

// ---------------- layout_bbox -> NHWC8 bf16 (+ weight prep in first 114 blocks)
__global__ __launch_bounds__(128) void layout_prep_kernel(
    const float* __restrict__ image, const float* __restrict__ w1,
    const float* __restrict__ w2, u16* __restrict__ lay8,
    u16* __restrict__ wB1, u16* __restrict__ wB2, float* __restrict__ st) {
  int h = blockIdx.x, b = blockIdx.y;
  int tid = threadIdx.x;
  int bid = b * 108 + h;
  if (bid < 114) {  // 114 * 512 = 58368 prep items
#pragma unroll
    for (int j = 0; j < 4; ++j) {
      int i = bid * 512 + j * 128 + tid;
      if (i < 1216) st[i] = 0.f;
      if (i < 7168) {
        int co = i / 224, k = i % 224;
        int chunk = k >> 5, kk = k & 31, tl = kk >> 3, ci = kk & 7;
        int tap = chunk * 4 + tl;
        unsigned v = 0;
        if (tap < 25 && ci < 7) v = f2bf(w1[co * 175 + ci * 25 + tap]);
        wB1[i] = (u16)v;
      } else if (i < 58368) {
        int jj = i - 7168;  // < 51200
        int tap = jj / 2048, r = jj % 2048, co = r >> 5, ci = r & 31;
        wB2[jj] = (u16)f2bf(w2[co * 800 + ci * 25 + tap]);
      }
    }
  }
  __shared__ float sIm[NOBJ * 11];
  for (int i = tid; i < NOBJ * 11; i += 128) sIm[i] = image[b * NOBJ * 11 + i];
  __syncthreads();
  int w = tid;
  if (w >= HW) return;
  float best[NCLS];
#pragma unroll
  for (int c = 0; c < NCLS; ++c) best[c] = 0.0f;
  float fw = (float)w, fh = (float)h;
  for (int o = 0; o < NOBJ; ++o) {
    const float* p = &sIm[o * 11];
    float xc = p[0] * 108.0f, yc = p[1] * 108.0f;
    float wd = p[2] * 108.0f, hd = p[3] * 108.0f;
    float x1 = xc - 0.5f * wd, x2 = xc + 0.5f * wd;
    float y1 = yc - 0.5f * hd, y2 = yc + 0.5f * hd;
    float x1d = fw - x1, x2d = x2 - fw;
    float y1d = fh - y1, y2d = y2 - fh;
    float yband = CLIP01(y1d) * CLIP01(y2d);
    float xband = CLIP01(x1d) * CLIP01(x2d);
    float x1l = fmaxf(1.0f - fabsf(x1d), 0.0f) * yband;
    float x2l = fmaxf(1.0f - fabsf(x2d), 0.0f) * yband;
    float y1l = fmaxf(1.0f - fabsf(y1d), 0.0f) * xband;
    float y2l = fmaxf(1.0f - fabsf(y2d), 0.0f) * xband;
    float xy = fmaxf(fmaxf(x1l, x2l), fmaxf(y1l, y2l));
#pragma unroll
    for (int c = 0; c < NCLS; ++c) best[c] = fmaxf(best[c], xy * p[4 + c]);
  }
  unsigned p0 = f2bf(best[0]) | (f2bf(best[1]) << 16);
  unsigned p1 = f2bf(best[2]) | (f2bf(best[3]) << 16);
  unsigned p2 = f2bf(best[4]) | (f2bf(best[5]) << 16);
  unsigned p3 = f2bf(best[6]);
  uint4 stv = {p0, p1, p2, p3};
  ((uint4*)lay8)[b * 11664 + h * 108 + w] = stv;
}

// --------------------------------------------------------------- conv1 MFMA
// grid (43 mt4, 2 nt, 16 bz), block 128 = 2 waves.
// wave: 4 m-tiles, 1 n-tile, 2 batches. BN1 stats: lane xor-reduce +
// cross-wave LDS reduce -> 1 atomic/block/co (688/address).
__global__ __launch_bounds__(128) void conv1_mfma(
    const u16* __restrict__ lay8, const u16* __restrict__ wB1,
    u16* __restrict__ x1r, float* __restrict__ bn1sum,
    float* __restrict__ bn1sq) {
  int mtg = blockIdx.x, nt = blockIdx.y, bz = blockIdx.z;
  int tid = threadIdx.x;
  int lane = tid & 63, wv = tid >> 6;
  int f = lane & 15, q = lane >> 4;
  int co = nt * 16 + f;
  int b0 = bz * 4 + wv * 2;
  int pbase[4];
  bool mvalid[4];
#pragma unroll
  for (int t = 0; t < 4; ++t) {
    int mt = mtg * 4 + t;
    mvalid[t] = mt < 169;
    int P = min(mt * 16 + f, 2703);
    int oh = P / 52, ow = P - oh * 52;
    pbase[t] = (oh * 2 * 108 + ow * 2) * 8;
  }
  f4_t acc[2][4];
#pragma unroll
  for (int b2 = 0; b2 < 2; ++b2)
#pragma unroll
    for (int t = 0; t < 4; ++t) acc[b2][t] = {0.f, 0.f, 0.f, 0.f};
#pragma unroll
  for (int chunk = 0; chunk < 7; ++chunk) {
    int tap = chunk * 4 + q;
    tap = tap > 24 ? 24 : tap;  // dup taps carry zero weights
    int kh = tap / 5, kw = tap - kh * 5;
    int toff = (kh * 108 + kw) * 8;
    bf8_t bf = *(const bf8_t*)&wB1[co * 224 + chunk * 32 + q * 8];
#pragma unroll
    for (int b2 = 0; b2 < 2; ++b2) {
      const u16* lb = lay8 + (size_t)(b0 + b2) * 93312;
#pragma unroll
      for (int t = 0; t < 4; ++t) {
        bf8_t af = *(const bf8_t*)&lb[pbase[t] + toff];
        acc[b2][t] = MFMA16(af, bf, acc[b2][t]);
      }
    }
  }
  float s = 0.f, sq = 0.f;
#pragma unroll
  for (int b2 = 0; b2 < 2; ++b2) {
    u16* ob = x1r + (size_t)(b0 + b2) * 86528;
#pragma unroll
    for (int t = 0; t < 4; ++t) {
      if (!mvalid[t]) continue;
      int P0 = (mtg * 4 + t) * 16 + q * 4;
#pragma unroll
      for (int r = 0; r < 4; ++r) {
        float v = acc[b2][t][r];
        s += v;
        sq += v * v;
        ob[(P0 + r) * 32 + co] = (u16)f2bf(v);
      }
    }
  }
  s += __shfl_xor(s, 16);
  s += __shfl_xor(s, 32);
  sq += __shfl_xor(sq, 16);
  sq += __shfl_xor(sq, 32);
  __shared__ float rs[2][16], rq[2][16];
  if (lane < 16) {
    rs[wv][f] = s;
    rq[wv][f] = sq;
  }
  __syncthreads();
  if (tid < 16) {
    atomicAdd(&bn1sum[nt * 16 + tid], rs[0][tid] + rs[1][tid]);
    atomicAdd(&bn1sq[nt * 16 + tid], rq[0][tid] + rq[1][tid]);
  }
}

// ------------- BN1 finalize(inline)+leaky: x1r bf16 -> x1b bf16, 8/thread
__global__ __launch_bounds__(256) void bnapply1_kernel(
    const u16* __restrict__ x1r, const float* __restrict__ bn1sum,
    const float* __restrict__ bn1sq, const float* __restrict__ g1,
    const float* __restrict__ b1, u16* __restrict__ x1b) {
  int idx = blockIdx.x * 256 + threadIdx.x;  // 692,224
  int base = idx * 8, c0 = base & 31;
  float sc[8], sh[8];
#pragma unroll
  for (int j = 0; j < 8; ++j) {
    int c = c0 + j;
    float mean = bn1sum[c] * (1.f / 173056.f);
    float var = bn1sq[c] * (1.f / 173056.f) - mean * mean;
    float s = g1[c] * rsqrtf(var + 1e-5f);
    sc[j] = s;
    sh[j] = b1[c] - mean * s;
  }
  uint4 in = *(const uint4*)&x1r[base];
  unsigned w[4] = {in.x, in.y, in.z, in.w};
  unsigned out[4];
#pragma unroll
  for (int j = 0; j < 4; ++j) {
    float a = bf2f(w[j] & 0xffffu);
    float bq = bf2f(w[j] >> 16);
    a = LEAKY(fmaf(a, sc[2 * j], sh[2 * j]));
    bq = LEAKY(fmaf(bq, sc[2 * j + 1], sh[2 * j + 1]));
    out[j] = f2bf(a) | (f2bf(bq) << 16);
  }
  uint4 stv = {out[0], out[1], out[2], out[3]};
  *(uint4*)&x1b[base] = stv;
}

// --------------------------------------------------------------- conv2 MFMA
// grid (36 mt, 4 nt, 4 bz), block 256 = 4 waves.
// wave: 1 m-tile, 1 n-tile, 4 batches (bz*16 + wv*4 + b2). LDS-free compute;
// BN2 stats (fp32, pre-rounding) via cross-wave LDS reduce -> 144/address.
// Output bf16 NHWC x2b[b][576][64].
__global__ __launch_bounds__(256) void conv2_mfma(
    const u16* __restrict__ x1b, const u16* __restrict__ wB2,
    u16* __restrict__ x2b, float* __restrict__ bn2sum,
    float* __restrict__ bn2sq) {
  int mt = blockIdx.x, nt = blockIdx.y, bz = blockIdx.z;
  int tid = threadIdx.x;
  int lane = tid & 63, wv = tid >> 6;
  int f = lane & 15, q = lane >> 4;
  int co = nt * 16 + f;
  int b0 = bz * 16 + wv * 4;
  int P = mt * 16 + f;
  int oh = P / 24, ow = P - oh * 24;
  int abase = (oh * 2 * 52 + ow * 2) * 32 + q * 8;
  f4_t acc[4];
#pragma unroll
  for (int b2 = 0; b2 < 4; ++b2) acc[b2] = {0.f, 0.f, 0.f, 0.f};
#pragma unroll
  for (int tap = 0; tap < 25; ++tap) {
    int kh = tap / 5, kw = tap - kh * 5;
    int toff = (kh * 52 + kw) * 32;
    bf8_t bf = *(const bf8_t*)&wB2[tap * 2048 + co * 32 + q * 8];
#pragma unroll
    for (int b2 = 0; b2 < 4; ++b2) {
      bf8_t af =
          *(const bf8_t*)&x1b[(size_t)(b0 + b2) * 86528 + abase + toff];
      acc[b2] = MFMA16(af, bf, acc[b2]);
    }
  }
  float s = 0.f, sq = 0.f;
#pragma unroll
  for (int b2 = 0; b2 < 4; ++b2) {
    u16* ob = x2b + (size_t)(b0 + b2) * 36864;
#pragma unroll
    for (int r = 0; r < 4; ++r) {
      float v = acc[b2][r];
      s += v;
      sq += v * v;
      ob[(mt * 16 + q * 4 + r) * 64 + co] = (u16)f2bf(v);
    }
  }
  s += __shfl_xor(s, 16);
  s += __shfl_xor(s, 32);
  sq += __shfl_xor(sq, 16);
  sq += __shfl_xor(sq, 32);
  __shared__ float rs[4][16], rq[4][16];
  if (lane < 16) {
    rs[wv][f] = s;
    rq[wv][f] = sq;
  }
  __syncthreads();
  if (tid < 16) {
    atomicAdd(&bn2sum[nt * 16 + tid],
              rs[0][tid] + rs[1][tid] + rs[2][tid] + rs[3][tid]);
    atomicAdd(&bn2sq[nt * 16 + tid],
              rq[0][tid] + rq[1][tid] + rq[2][tid] + rq[3][tid]);
  }
}

// ---- BN2 finalize(inline)+leaky + NHWC->NCHW: x2b bf16 -> xB bf16 [b][64*576]
__global__ __launch_bounds__(256) void bnapply2t_kernel(
    const u16* __restrict__ x2b, const float* __restrict__ bn2sum,
    const float* __restrict__ bn2sq, const float* __restrict__ g2,
    const float* __restrict__ b2, u16* __restrict__ xB) {
  int hw0 = blockIdx.x * 64, b = blockIdx.y;
  __shared__ float tile[64 * 65];
  int t = threadIdx.x;
  int c = t & 63, hl4 = t >> 6;
  float mean = bn2sum[c] * (1.f / 36864.f);
  float var = bn2sq[c] * (1.f / 36864.f) - mean * mean;
  float s = g2[c] * rsqrtf(var + 1e-5f);
  float h = b2[c] - mean * s;
#pragma unroll
  for (int it = 0; it < 16; ++it) {
    int hl = it * 4 + hl4;
    float v = bf2f((unsigned)x2b[((size_t)b * 576 + hw0 + hl) * 64 + c]);
    tile[hl * 65 + c] = LEAKY(fmaf(v, s, h));
  }
  __syncthreads();
  int hw = t & 63, cl4 = t >> 6;
#pragma unroll
  for (int it = 0; it < 16; ++it) {
    int cc = it * 4 + cl4;
    xB[(size_t)b * 36864 + cc * 576 + hw0 + hw] = (u16)f2bf(tile[hw * 65 + cc]);
  }
}

// ----------------------------------------------------------------- fc1 MFMA
// part[ks][64][512]: A bf16 [64][36864] x W fp32[512][36864] (cvt in-flight).
// grid (72 ks, 8 nb), block 256 = 4 waves; A staged once (row pad 520 u16 ->
// 2-way bank alias only); K loop barrier-free.
__global__ __launch_bounds__(256) void fc1_mfma(
    const u16* __restrict__ xB, const float* __restrict__ wgt,
    float* __restrict__ part) {
  int ks = blockIdx.x, nb = blockIdx.y;
  int tid = threadIdx.x;
  int lane = tid & 63, wv = tid >> 6;
  int f = lane & 15, q = lane >> 4;
  int n0 = nb * 64 + wv * 16;
  int kbase = ks * 512;
  __shared__ u16 sA[64 * 520];
#pragma unroll
  for (int i = 0; i < 16; ++i) {
    int c = i * 256 + tid;           // 0..4095
    int row = c >> 6, col = c & 63;  // col in uint4 (8-u16) units
    *(uint4*)&sA[row * 520 + col * 8] =
        *(const uint4*)&xB[(size_t)row * 36864 + kbase + col * 8];
  }
  __syncthreads();
  f4_t acc[4];
#pragma unroll
  for (int m = 0; m < 4; ++m) acc[m] = {0.f, 0.f, 0.f, 0.f};
  const float* wrow = wgt + (size_t)(n0 + f) * 36864 + kbase + q * 8;
#pragma unroll 4
  for (int kt = 0; kt < 16; ++kt) {
    const float* wp = wrow + kt * 32;
    float4 wa = *(const float4*)wp;
    float4 wb = *(const float4*)(wp + 4);
    union { bf8_t v; u16 u[8]; } bu;
    bu.u[0] = (u16)f2bf(wa.x); bu.u[1] = (u16)f2bf(wa.y);
    bu.u[2] = (u16)f2bf(wa.z); bu.u[3] = (u16)f2bf(wa.w);
    bu.u[4] = (u16)f2bf(wb.x); bu.u[5] = (u16)f2bf(wb.y);
    bu.u[6] = (u16)f2bf(wb.z); bu.u[7] = (u16)f2bf(wb.w);
    bf8_t afr[4];
#pragma unroll
    for (int m = 0; m < 4; ++m)
      afr[m] = *(const bf8_t*)&sA[(m * 16 + f) * 520 + kt * 32 + q * 8];
#pragma unroll
    for (int m = 0; m < 4; ++m) acc[m] = MFMA16(afr[m], bu.v, acc[m]);
  }
  float* pp = part + (size_t)ks * 32768;
#pragma unroll
  for (int m = 0; m < 4; ++m)
#pragma unroll
    for (int r = 0; r < 4; ++r)
      pp[(m * 16 + q * 4 + r) * 512 + n0 + f] = acc[m][r];
}

// --------------- fc1_reduce: sum 72 partials -> fc1o; fused BN3 stat atomics
__global__ __launch_bounds__(256) void fc1_reduce_kernel(
    const float* __restrict__ part, float* __restrict__ fc1o,
    float* __restrict__ bn3sum, float* __restrict__ bn3sq) {
  int i = blockIdx.x * 256 + threadIdx.x;  // 0..32767
  float s = 0.f;
#pragma unroll 8
  for (int ks = 0; ks < 72; ++ks) s += part[(size_t)ks * 32768 + i];
  fc1o[i] = s;
  atomicAdd(&bn3sum[i & 511], s);
  atomicAdd(&bn3sq[i & 511], s * s);
}

// ------------------------- fc2: BN3 inline + leaky + dot + sigmoid
__global__ __launch_bounds__(64) void fc2_kernel(
    const float* __restrict__ fc1o, const float* __restrict__ bn3sum,
    const float* __restrict__ bn3sq, const float* __restrict__ g3,
    const float* __restrict__ b3, const float* __restrict__ w2,
    const float* __restrict__ b2o, float* __restrict__ out) {
  int m = blockIdx.x;
  int fl = threadIdx.x;
  float a = 0.f;
#pragma unroll
  for (int j = 0; j < 8; ++j) {
    int ff = fl + j * 64;
    float mean = bn3sum[ff] * (1.f / 64.f);
    float var = bn3sq[ff] * (1.f / 64.f) - mean * mean;
    float sc = g3[ff] * rsqrtf(var + 1e-5f);
    float sh = b3[ff] - mean * sc;
    float v = LEAKY(fmaf(fc1o[m * 512 + ff], sc, sh));
    a += v * w2[ff];
  }
  for (int off = 32; off; off >>= 1) a += __shfl_down(a, off, 64);
  if (fl == 0) out[m] = 1.f / (1.f + expf(-(a + b2o[0])));
}

extern "C" void kernel_launch(void* const* d_in, const int* in_sizes, int n_in,
                              void* d_out, int out_size, void* d_ws,
                              size_t ws_size, hipStream_t stream) {
  const float* image = (const float*)d_in[0];
  const float* c1w = (const float*)d_in[1];
  const float* bn1g = (const float*)d_in[3];
  const float* bn1b = (const float*)d_in[4];
  const float* c2w = (const float*)d_in[5];
  const float* bn2g = (const float*)d_in[7];
  const float* bn2b = (const float*)d_in[8];
  const float* f1w = (const float*)d_in[9];
  const float* bn3g = (const float*)d_in[11];
  const float* bn3b = (const float*)d_in[12];
  const float* f2w = (const float*)d_in[13];
  const float* f2b = (const float*)d_in[14];
  float* ws = (float*)d_ws;

  // Workspace (float units), linear (~53 MB of 302 MB; no aliasing):
  u16* lay8 = (u16*)ws;                    // @0          (2,985,984 f)
  u16* x1r = (u16*)(ws + 2985984);         // 2,768,896 f
  u16* x1b = (u16*)(ws + 5754880);         // 2,768,896 f
  u16* x2b = (u16*)(ws + 8523776);         // 1,179,648 f
  u16* xB = (u16*)(ws + 9703424);          // 1,179,648 f
  float* fc1part = ws + 10883072;          // 2,359,296 f (72*32768)
  float* fc1o = ws + 13242368;             // 32,768 f
  float* st = ws + 13275136;               // 1,216 f (zeroed by layout_prep)
  float* bn1sum = st, *bn1sq = st + 32;
  float* bn2sum = st + 64, *bn2sq = st + 128;
  float* bn3sum = st + 192, *bn3sq = st + 704;
  u16* wB1 = (u16*)(ws + 13276352);        // 7,168 u16
  u16* wB2 = (u16*)(ws + 13279936);        // 51,200 u16

  layout_prep_kernel<<<dim3(108, 64), 128, 0, stream>>>(image, c1w, c2w, lay8,
                                                        wB1, wB2, st);
  conv1_mfma<<<dim3(43, 2, 16), 128, 0, stream>>>(lay8, wB1, x1r, bn1sum,
                                                  bn1sq);
  bnapply1_kernel<<<2704, 256, 0, stream>>>(x1r, bn1sum, bn1sq, bn1g, bn1b,
                                            x1b);
  conv2_mfma<<<dim3(36, 4, 4), 256, 0, stream>>>(x1b, wB2, x2b, bn2sum,
                                                 bn2sq);
  bnapply2t_kernel<<<dim3(9, 64), 256, 0, stream>>>(x2b, bn2sum, bn2sq, bn2g,
                                                    bn2b, xB);
  fc1_mfma<<<dim3(72, 8), 256, 0, stream>>>(xB, f1w, fc1part);
  fc1_reduce_kernel<<<128, 256, 0, stream>>>(fc1part, fc1o, bn3sum, bn3sq);
  fc2_kernel<<<64, 64, 0, stream>>>(fc1o, bn3sum, bn3sq, bn3g, bn3b, f2w, f2b,
                                    (float*)d_out);
}

// Round 10
// 239.400 us; speedup vs baseline: 1.1096x; 1.0428x over previous
//
#include <hip/hip_runtime.h>
#include <hip/hip_bf16.h>

// Discriminator pipeline. R10 = R9 + conv2 reads A once per 2 n-tiles
// (halves redundant A-fragment L1/L2 traffic). 8 dispatches:
//   layout(+wprep +zero stats) -> conv1(+BN1 stats) -> bnapply1 (BN1 inline)
//   -> conv2(2 n-tiles x 4 batches/wave, +BN2 stats, bf16 out)
//   -> bnapply2t (BN2 inline) -> fc1 (LDS-staged A, 72-way split-K)
//   -> fc1_reduce(+BN3 stats) -> fc2 (BN3 inline + sigmoid).
// conv/fc biases absorbed by the following BN. BN scale/shift computed
// redundantly per consumer block from fp32 atomic sums.
//
// MFMA convention (verified m89/m91): D = mfma(a,b,c): D[m][n] = sum_k
// A[m][k]*B[n][k]; a: lane(f=m&15,q=lane>>4) elem j = A[f][q*8+j]; b same
// with f=n; d: lane l reg r = D[(l>>4)*4+r][l&15].
// fc1 LDS tile pad: row stride 520 u16 = 260 words = 4 mod 32 -> 2-way bank
// alias only (free per m136). Do NOT remove the pad (32-row stride = 8-way).

typedef unsigned short u16;
typedef __attribute__((ext_vector_type(8))) short bf8_t;
typedef __attribute__((ext_vector_type(4))) float f4_t;
#define MFMA16(a, b, c) __builtin_amdgcn_mfma_f32_16x16x32_bf16(a, b, c, 0, 0, 0)

#define LEAKY(v) (fmaxf((v), 0.2f * (v)))
#define CLIP01(v) fminf(fmaxf((v), 0.0f), 1.0f)

__device__ inline unsigned f2bf(float f) {  // RNE fp32->bf16 (low 16 bits)
  unsigned u = __float_as_uint(f);
  return (u + 0x7FFFu + ((u >> 16) & 1u)) >> 16;
}
__device__ inline float bf2f(unsigned u) { return __uint_as_float(u << 16); }

constexpr int HW = 108;
constexpr int NOBJ = 16;
constexpr int NCLS = 7;

// ---------------- layout_bbox -> NHWC8 bf16 (+ weight prep in first 114 blocks)
__global__ __launch_bounds__(128) void layout_prep_kernel(
    const float* __restrict__ image, const float* __restrict__ w1,
    const float* __restrict__ w2, u16* __restrict__ lay8,
    u16* __restrict__ wB1, u16* __restrict__ wB2, float* __restrict__ st) {
  int h = blockIdx.x, b = blockIdx.y;
  int tid = threadIdx.x;
  int bid = b * 108 + h;
  if (bid < 114) {  // 114 * 512 = 58368 prep items
#pragma unroll
    for (int j = 0; j < 4; ++j) {
      int i = bid * 512 + j * 128 + tid;
      if (i < 1216) st[i] = 0.f;
      if (i < 7168) {
        int co = i / 224, k = i % 224;
        int chunk = k >> 5, kk = k & 31, tl = kk >> 3, ci = kk & 7;
        int tap = chunk * 4 + tl;
        unsigned v = 0;
        if (tap < 25 && ci < 7) v = f2bf(w1[co * 175 + ci * 25 + tap]);
        wB1[i] = (u16)v;
      } else if (i < 58368) {
        int jj = i - 7168;  // < 51200
        int tap = jj / 2048, r = jj % 2048, co = r >> 5, ci = r & 31;
        wB2[jj] = (u16)f2bf(w2[co * 800 + ci * 25 + tap]);
      }
    }
  }
  __shared__ float sIm[NOBJ * 11];
  for (int i = tid; i < NOBJ * 11; i += 128) sIm[i] = image[b * NOBJ * 11 + i];
  __syncthreads();
  int w = tid;
  if (w >= HW) return;
  float best[NCLS];
#pragma unroll
  for (int c = 0; c < NCLS; ++c) best[c] = 0.0f;
  float fw = (float)w, fh = (float)h;
  for (int o = 0; o < NOBJ; ++o) {
    const float* p = &sIm[o * 11];
    float xc = p[0] * 108.0f, yc = p[1] * 108.0f;
    float wd = p[2] * 108.0f, hd = p[3] * 108.0f;
    float x1 = xc - 0.5f * wd, x2 = xc + 0.5f * wd;
    float y1 = yc - 0.5f * hd, y2 = yc + 0.5f * hd;
    float x1d = fw - x1, x2d = x2 - fw;
    float y1d = fh - y1, y2d = y2 - fh;
    float yband = CLIP01(y1d) * CLIP01(y2d);
    float xband = CLIP01(x1d) * CLIP01(x2d);
    float x1l = fmaxf(1.0f - fabsf(x1d), 0.0f) * yband;
    float x2l = fmaxf(1.0f - fabsf(x2d), 0.0f) * yband;
    float y1l = fmaxf(1.0f - fabsf(y1d), 0.0f) * xband;
    float y2l = fmaxf(1.0f - fabsf(y2d), 0.0f) * xband;
    float xy = fmaxf(fmaxf(x1l, x2l), fmaxf(y1l, y2l));
#pragma unroll
    for (int c = 0; c < NCLS; ++c) best[c] = fmaxf(best[c], xy * p[4 + c]);
  }
  unsigned p0 = f2bf(best[0]) | (f2bf(best[1]) << 16);
  unsigned p1 = f2bf(best[2]) | (f2bf(best[3]) << 16);
  unsigned p2 = f2bf(best[4]) | (f2bf(best[5]) << 16);
  unsigned p3 = f2bf(best[6]);
  uint4 stv = {p0, p1, p2, p3};
  ((uint4*)lay8)[b * 11664 + h * 108 + w] = stv;
}

// --------------------------------------------------------------- conv1 MFMA
// grid (43 mt4, 2 nt, 16 bz), block 128 = 2 waves.
// wave: 4 m-tiles, 1 n-tile, 2 batches. BN1 stats: lane xor-reduce +
// cross-wave LDS reduce -> 1 atomic/block/co (688/address).
__global__ __launch_bounds__(128) void conv1_mfma(
    const u16* __restrict__ lay8, const u16* __restrict__ wB1,
    u16* __restrict__ x1r, float* __restrict__ bn1sum,
    float* __restrict__ bn1sq) {
  int mtg = blockIdx.x, nt = blockIdx.y, bz = blockIdx.z;
  int tid = threadIdx.x;
  int lane = tid & 63, wv = tid >> 6;
  int f = lane & 15, q = lane >> 4;
  int co = nt * 16 + f;
  int b0 = bz * 4 + wv * 2;
  int pbase[4];
  bool mvalid[4];
#pragma unroll
  for (int t = 0; t < 4; ++t) {
    int mt = mtg * 4 + t;
    mvalid[t] = mt < 169;
    int P = min(mt * 16 + f, 2703);
    int oh = P / 52, ow = P - oh * 52;
    pbase[t] = (oh * 2 * 108 + ow * 2) * 8;
  }
  f4_t acc[2][4];
#pragma unroll
  for (int b2 = 0; b2 < 2; ++b2)
#pragma unroll
    for (int t = 0; t < 4; ++t) acc[b2][t] = {0.f, 0.f, 0.f, 0.f};
#pragma unroll
  for (int chunk = 0; chunk < 7; ++chunk) {
    int tap = chunk * 4 + q;
    tap = tap > 24 ? 24 : tap;  // dup taps carry zero weights
    int kh = tap / 5, kw = tap - kh * 5;
    int toff = (kh * 108 + kw) * 8;
    bf8_t bf = *(const bf8_t*)&wB1[co * 224 + chunk * 32 + q * 8];
#pragma unroll
    for (int b2 = 0; b2 < 2; ++b2) {
      const u16* lb = lay8 + (size_t)(b0 + b2) * 93312;
#pragma unroll
      for (int t = 0; t < 4; ++t) {
        bf8_t af = *(const bf8_t*)&lb[pbase[t] + toff];
        acc[b2][t] = MFMA16(af, bf, acc[b2][t]);
      }
    }
  }
  float s = 0.f, sq = 0.f;
#pragma unroll
  for (int b2 = 0; b2 < 2; ++b2) {
    u16* ob = x1r + (size_t)(b0 + b2) * 86528;
#pragma unroll
    for (int t = 0; t < 4; ++t) {
      if (!mvalid[t]) continue;
      int P0 = (mtg * 4 + t) * 16 + q * 4;
#pragma unroll
      for (int r = 0; r < 4; ++r) {
        float v = acc[b2][t][r];
        s += v;
        sq += v * v;
        ob[(P0 + r) * 32 + co] = (u16)f2bf(v);
      }
    }
  }
  s += __shfl_xor(s, 16);
  s += __shfl_xor(s, 32);
  sq += __shfl_xor(sq, 16);
  sq += __shfl_xor(sq, 32);
  __shared__ float rs[2][16], rq[2][16];
  if (lane < 16) {
    rs[wv][f] = s;
    rq[wv][f] = sq;
  }
  __syncthreads();
  if (tid < 16) {
    atomicAdd(&bn1sum[nt * 16 + tid], rs[0][tid] + rs[1][tid]);
    atomicAdd(&bn1sq[nt * 16 + tid], rq[0][tid] + rq[1][tid]);
  }
}

// ------------- BN1 finalize(inline)+leaky: x1r bf16 -> x1b bf16, 8/thread
__global__ __launch_bounds__(256) void bnapply1_kernel(
    const u16* __restrict__ x1r, const float* __restrict__ bn1sum,
    const float* __restrict__ bn1sq, const float* __restrict__ g1,
    const float* __restrict__ b1, u16* __restrict__ x1b) {
  int idx = blockIdx.x * 256 + threadIdx.x;  // 692,224
  int base = idx * 8, c0 = base & 31;
  float sc[8], sh[8];
#pragma unroll
  for (int j = 0; j < 8; ++j) {
    int c = c0 + j;
    float mean = bn1sum[c] * (1.f / 173056.f);
    float var = bn1sq[c] * (1.f / 173056.f) - mean * mean;
    float s = g1[c] * rsqrtf(var + 1e-5f);
    sc[j] = s;
    sh[j] = b1[c] - mean * s;
  }
  uint4 in = *(const uint4*)&x1r[base];
  unsigned w[4] = {in.x, in.y, in.z, in.w};
  unsigned out[4];
#pragma unroll
  for (int j = 0; j < 4; ++j) {
    float a = bf2f(w[j] & 0xffffu);
    float bq = bf2f(w[j] >> 16);
    a = LEAKY(fmaf(a, sc[2 * j], sh[2 * j]));
    bq = LEAKY(fmaf(bq, sc[2 * j + 1], sh[2 * j + 1]));
    out[j] = f2bf(a) | (f2bf(bq) << 16);
  }
  uint4 stv = {out[0], out[1], out[2], out[3]};
  *(uint4*)&x1b[base] = stv;
}

// --------------------------------------------------------------- conv2 MFMA
// grid (36 mt, 2 ntg, 4 bz), block 256 = 4 waves.
// wave: 1 m-tile, 2 n-tiles (co ntg*32 .. +31), 4 batches (bz*16 + wv*4 +
// b2). Each A-fragment is loaded once and feeds 2 MFMAs (halves A-traffic
// vs 1-n-tile waves). BN2 stats (fp32, pre-rounding) via cross-wave LDS
// reduce -> 144 atomics/address. Output bf16 NHWC x2b[b][576][64].
__global__ __launch_bounds__(256) void conv2_mfma(
    const u16* __restrict__ x1b, const u16* __restrict__ wB2,
    u16* __restrict__ x2b, float* __restrict__ bn2sum,
    float* __restrict__ bn2sq) {
  int mt = blockIdx.x, ntg = blockIdx.y, bz = blockIdx.z;
  int tid = threadIdx.x;
  int lane = tid & 63, wv = tid >> 6;
  int f = lane & 15, q = lane >> 4;
  int co0 = ntg * 32;
  int b0 = bz * 16 + wv * 4;
  int P = mt * 16 + f;
  int oh = P / 24, ow = P - oh * 24;
  int abase = (oh * 2 * 52 + ow * 2) * 32 + q * 8;
  f4_t acc[4][2];
#pragma unroll
  for (int b2 = 0; b2 < 4; ++b2)
#pragma unroll
    for (int n = 0; n < 2; ++n) acc[b2][n] = {0.f, 0.f, 0.f, 0.f};
#pragma unroll
  for (int tap = 0; tap < 25; ++tap) {
    int kh = tap / 5, kw = tap - kh * 5;
    int toff = (kh * 52 + kw) * 32;
    bf8_t bf0 = *(const bf8_t*)&wB2[tap * 2048 + (co0 + f) * 32 + q * 8];
    bf8_t bf1 = *(const bf8_t*)&wB2[tap * 2048 + (co0 + 16 + f) * 32 + q * 8];
#pragma unroll
    for (int b2 = 0; b2 < 4; ++b2) {
      bf8_t af =
          *(const bf8_t*)&x1b[(size_t)(b0 + b2) * 86528 + abase + toff];
      acc[b2][0] = MFMA16(af, bf0, acc[b2][0]);
      acc[b2][1] = MFMA16(af, bf1, acc[b2][1]);
    }
  }
  float s[2] = {0.f, 0.f}, sq[2] = {0.f, 0.f};
#pragma unroll
  for (int b2 = 0; b2 < 4; ++b2) {
    u16* ob = x2b + (size_t)(b0 + b2) * 36864;
#pragma unroll
    for (int n = 0; n < 2; ++n)
#pragma unroll
      for (int r = 0; r < 4; ++r) {
        float v = acc[b2][n][r];
        s[n] += v;
        sq[n] += v * v;
        ob[(mt * 16 + q * 4 + r) * 64 + co0 + n * 16 + f] = (u16)f2bf(v);
      }
  }
#pragma unroll
  for (int n = 0; n < 2; ++n) {
    s[n] += __shfl_xor(s[n], 16);
    s[n] += __shfl_xor(s[n], 32);
    sq[n] += __shfl_xor(sq[n], 16);
    sq[n] += __shfl_xor(sq[n], 32);
  }
  __shared__ float rs[4][32], rq[4][32];
  if (lane < 16) {
#pragma unroll
    for (int n = 0; n < 2; ++n) {
      rs[wv][n * 16 + f] = s[n];
      rq[wv][n * 16 + f] = sq[n];
    }
  }
  __syncthreads();
  if (tid < 32) {
    atomicAdd(&bn2sum[co0 + tid],
              rs[0][tid] + rs[1][tid] + rs[2][tid] + rs[3][tid]);
    atomicAdd(&bn2sq[co0 + tid],
              rq[0][tid] + rq[1][tid] + rq[2][tid] + rq[3][tid]);
  }
}

// ---- BN2 finalize(inline)+leaky + NHWC->NCHW: x2b bf16 -> xB bf16 [b][64*576]
__global__ __launch_bounds__(256) void bnapply2t_kernel(
    const u16* __restrict__ x2b, const float* __restrict__ bn2sum,
    const float* __restrict__ bn2sq, const float* __restrict__ g2,
    const float* __restrict__ b2, u16* __restrict__ xB) {
  int hw0 = blockIdx.x * 64, b = blockIdx.y;
  __shared__ float tile[64 * 65];
  int t = threadIdx.x;
  int c = t & 63, hl4 = t >> 6;
  float mean = bn2sum[c] * (1.f / 36864.f);
  float var = bn2sq[c] * (1.f / 36864.f) - mean * mean;
  float s = g2[c] * rsqrtf(var + 1e-5f);
  float h = b2[c] - mean * s;
#pragma unroll
  for (int it = 0; it < 16; ++it) {
    int hl = it * 4 + hl4;
    float v = bf2f((unsigned)x2b[((size_t)b * 576 + hw0 + hl) * 64 + c]);
    tile[hl * 65 + c] = LEAKY(fmaf(v, s, h));
  }
  __syncthreads();
  int hw = t & 63, cl4 = t >> 6;
#pragma unroll
  for (int it = 0; it < 16; ++it) {
    int cc = it * 4 + cl4;
    xB[(size_t)b * 36864 + cc * 576 + hw0 + hw] = (u16)f2bf(tile[hw * 65 + cc]);
  }
}

// ----------------------------------------------------------------- fc1 MFMA
// part[ks][64][512]: A bf16 [64][36864] x W fp32[512][36864] (cvt in-flight).
// grid (72 ks, 8 nb), block 256 = 4 waves; A staged once (row pad 520 u16 ->
// 2-way bank alias only); K loop barrier-free.
__global__ __launch_bounds__(256) void fc1_mfma(
    const u16* __restrict__ xB, const float* __restrict__ wgt,
    float* __restrict__ part) {
  int ks = blockIdx.x, nb = blockIdx.y;
  int tid = threadIdx.x;
  int lane = tid & 63, wv = tid >> 6;
  int f = lane & 15, q = lane >> 4;
  int n0 = nb * 64 + wv * 16;
  int kbase = ks * 512;
  __shared__ u16 sA[64 * 520];
#pragma unroll
  for (int i = 0; i < 16; ++i) {
    int c = i * 256 + tid;           // 0..4095
    int row = c >> 6, col = c & 63;  // col in uint4 (8-u16) units
    *(uint4*)&sA[row * 520 + col * 8] =
        *(const uint4*)&xB[(size_t)row * 36864 + kbase + col * 8];
  }
  __syncthreads();
  f4_t acc[4];
#pragma unroll
  for (int m = 0; m < 4; ++m) acc[m] = {0.f, 0.f, 0.f, 0.f};
  const float* wrow = wgt + (size_t)(n0 + f) * 36864 + kbase + q * 8;
#pragma unroll 4
  for (int kt = 0; kt < 16; ++kt) {
    const float* wp = wrow + kt * 32;
    float4 wa = *(const float4*)wp;
    float4 wb = *(const float4*)(wp + 4);
    union { bf8_t v; u16 u[8]; } bu;
    bu.u[0] = (u16)f2bf(wa.x); bu.u[1] = (u16)f2bf(wa.y);
    bu.u[2] = (u16)f2bf(wa.z); bu.u[3] = (u16)f2bf(wa.w);
    bu.u[4] = (u16)f2bf(wb.x); bu.u[5] = (u16)f2bf(wb.y);
    bu.u[6] = (u16)f2bf(wb.z); bu.u[7] = (u16)f2bf(wb.w);
    bf8_t afr[4];
#pragma unroll
    for (int m = 0; m < 4; ++m)
      afr[m] = *(const bf8_t*)&sA[(m * 16 + f) * 520 + kt * 32 + q * 8];
#pragma unroll
    for (int m = 0; m < 4; ++m) acc[m] = MFMA16(afr[m], bu.v, acc[m]);
  }
  float* pp = part + (size_t)ks * 32768;
#pragma unroll
  for (int m = 0; m < 4; ++m)
#pragma unroll
    for (int r = 0; r < 4; ++r)
      pp[(m * 16 + q * 4 + r) * 512 + n0 + f] = acc[m][r];
}

// --------------- fc1_reduce: sum 72 partials -> fc1o; fused BN3 stat atomics
__global__ __launch_bounds__(256) void fc1_reduce_kernel(
    const float* __restrict__ part, float* __restrict__ fc1o,
    float* __restrict__ bn3sum, float* __restrict__ bn3sq) {
  int i = blockIdx.x * 256 + threadIdx.x;  // 0..32767
  float s = 0.f;
#pragma unroll 8
  for (int ks = 0; ks < 72; ++ks) s += part[(size_t)ks * 32768 + i];
  fc1o[i] = s;
  atomicAdd(&bn3sum[i & 511], s);
  atomicAdd(&bn3sq[i & 511], s * s);
}

// ------------------------- fc2: BN3 inline + leaky + dot + sigmoid
__global__ __launch_bounds__(64) void fc2_kernel(
    const float* __restrict__ fc1o, const float* __restrict__ bn3sum,
    const float* __restrict__ bn3sq, const float* __restrict__ g3,
    const float* __restrict__ b3, const float* __restrict__ w2,
    const float* __restrict__ b2o, float* __restrict__ out) {
  int m = blockIdx.x;
  int fl = threadIdx.x;
  float a = 0.f;
#pragma unroll
  for (int j = 0; j < 8; ++j) {
    int ff = fl + j * 64;
    float mean = bn3sum[ff] * (1.f / 64.f);
    float var = bn3sq[ff] * (1.f / 64.f) - mean * mean;
    float sc = g3[ff] * rsqrtf(var + 1e-5f);
    float sh = b3[ff] - mean * sc;
    float v = LEAKY(fmaf(fc1o[m * 512 + ff], sc, sh));
    a += v * w2[ff];
  }
  for (int off = 32; off; off >>= 1) a += __shfl_down(a, off, 64);
  if (fl == 0) out[m] = 1.f / (1.f + expf(-(a + b2o[0])));
}

extern "C" void kernel_launch(void* const* d_in, const int* in_sizes, int n_in,
                              void* d_out, int out_size, void* d_ws,
                              size_t ws_size, hipStream_t stream) {
  const float* image = (const float*)d_in[0];
  const float* c1w = (const float*)d_in[1];
  const float* bn1g = (const float*)d_in[3];
  const float* bn1b = (const float*)d_in[4];
  const float* c2w = (const float*)d_in[5];
  const float* bn2g = (const float*)d_in[7];
  const float* bn2b = (const float*)d_in[8];
  const float* f1w = (const float*)d_in[9];
  const float* bn3g = (const float*)d_in[11];
  const float* bn3b = (const float*)d_in[12];
  const float* f2w = (const float*)d_in[13];
  const float* f2b = (const float*)d_in[14];
  float* ws = (float*)d_ws;

  // Workspace (float units), linear (~53 MB of 302 MB; no aliasing):
  u16* lay8 = (u16*)ws;                    // @0          (2,985,984 f)
  u16* x1r = (u16*)(ws + 2985984);         // 2,768,896 f
  u16* x1b = (u16*)(ws + 5754880);         // 2,768,896 f
  u16* x2b = (u16*)(ws + 8523776);         // 1,179,648 f
  u16* xB = (u16*)(ws + 9703424);          // 1,179,648 f
  float* fc1part = ws + 10883072;          // 2,359,296 f (72*32768)
  float* fc1o = ws + 13242368;             // 32,768 f
  float* st = ws + 13275136;               // 1,216 f (zeroed by layout_prep)
  float* bn1sum = st, *bn1sq = st + 32;
  float* bn2sum = st + 64, *bn2sq = st + 128;
  float* bn3sum = st + 192, *bn3sq = st + 704;
  u16* wB1 = (u16*)(ws + 13276352);        // 7,168 u16
  u16* wB2 = (u16*)(ws + 13279936);        // 51,200 u16

  layout_prep_kernel<<<dim3(108, 64), 128, 0, stream>>>(image, c1w, c2w, lay8,
                                                        wB1, wB2, st);
  conv1_mfma<<<dim3(43, 2, 16), 128, 0, stream>>>(lay8, wB1, x1r, bn1sum,
                                                  bn1sq);
  bnapply1_kernel<<<2704, 256, 0, stream>>>(x1r, bn1sum, bn1sq, bn1g, bn1b,
                                            x1b);
  conv2_mfma<<<dim3(36, 2, 4), 256, 0, stream>>>(x1b, wB2, x2b, bn2sum,
                                                 bn2sq);
  bnapply2t_kernel<<<dim3(9, 64), 256, 0, stream>>>(x2b, bn2sum, bn2sq, bn2g,
                                                    bn2b, xB);
  fc1_mfma<<<dim3(72, 8), 256, 0, stream>>>(xB, f1w, fc1part);
  fc1_reduce_kernel<<<128, 256, 0, stream>>>(fc1part, fc1o, bn3sum, bn3sq);
  fc2_kernel<<<64, 64, 0, stream>>>(fc1o, bn3sum, bn3sq, bn3g, bn3b, f2w, f2b,
                                    (float*)d_out);
}